// Round 4
// baseline (303.422 us; speedup 1.0000x reference)
//
#include <hip/hip_runtime.h>
#include <hip/hip_bf16.h>
#include <stdint.h>
#include <string.h>

// Problem constants (fixed by the reference)
#define NUM_CHIPS 4
#define N_EXPERTS 32
#define TOP_K 4
#define SEQ 1024
#define HIDDEN 2048
#define MAX_TOK 1024
#define META_LEN 8
#define NPC (SEQ * TOP_K)            // 4096 assignments per chip
#define NTOT (NUM_CHIPS * NPC)       // 16384 assignments total
#define ROWS (N_EXPERTS * MAX_TOK)   // 32768 output rows
#define BUF_ELEMS ((size_t)ROWS * HIDDEN)           // 67,108,864
#define META_OFF BUF_ELEMS
#define CNT_OFF (BUF_ELEMS + (size_t)ROWS * META_LEN)

// Workspace layout (ints)
#define WS_RANK 0                    // [NTOT]  within-chip stable rank
#define WS_CNT  (NTOT)               // [4][32] per-chip per-expert counts
#define WS_TOT  (NTOT + 128)         // [32]    total per-expert counts
#define WS_INV  (NTOT + 128 + 32)    // [ROWS]  inverse map (only occupied slots written)

// Clang ext-vector type: __builtin_nontemporal_store accepts these
// (it rejects HIP's float4 class type).
typedef float vfloat4 __attribute__((ext_vector_type(4)));

// ---------------------------------------------------------------------------
// rank_kernel: one block per chip, 1024 threads. All 4096 expert ids are
// loaded into registers up-front (coalesced); 4 serial chunk iterations of
// ballot-rank + 16-wave LDS scan. ~4 us total.
// ---------------------------------------------------------------------------
__global__ __launch_bounds__(1024) void rank_kernel(const int* __restrict__ idx,
                                                    int* __restrict__ ws) {
    __shared__ int run_base[N_EXPERTS];       // running per-expert count
    __shared__ int wave_cnt[16][N_EXPERTS];   // per-wave group sizes in chunk
    __shared__ int wave_base[16][N_EXPERTS];  // exclusive base per wave

    const int c = blockIdx.x;
    const int t = threadIdx.x;
    const int lane = t & 63;
    const int w = t >> 6;

    int e[4];
#pragma unroll
    for (int q = 0; q < 4; ++q) e[q] = idx[c * NPC + q * 1024 + t];

    if (t < N_EXPERTS) run_base[t] = 0;
    __syncthreads();

#pragma unroll
    for (int q = 0; q < 4; ++q) {
        if (t < 16 * N_EXPERTS) ((int*)wave_cnt)[t] = 0;
        __syncthreads();

        // mask of lanes in this wave routed to the same expert
        uint64_t m = ~0ull;
#pragma unroll
        for (int b = 0; b < 5; ++b) {
            uint64_t bb = __ballot((e[q] >> b) & 1);
            m &= ((e[q] >> b) & 1) ? bb : ~bb;
        }
        const int rk = __popcll(m & ((1ull << lane) - 1ull));  // stable in-wave rank
        if (rk == 0) wave_cnt[w][e[q]] = __popcll(m);          // group leader
        __syncthreads();

        // cross-wave exclusive scan per expert, update running base
        if (t < N_EXPERTS) {
            int s = run_base[t];
#pragma unroll
            for (int ww = 0; ww < 16; ++ww) {
                wave_base[ww][t] = s;
                s += wave_cnt[ww][t];
            }
            run_base[t] = s;
        }
        __syncthreads();

        ws[WS_RANK + c * NPC + q * 1024 + t] = wave_base[w][e[q]] + rk;
        // next writes to wave_base occur only after two more __syncthreads().
    }
    __syncthreads();
    if (t < N_EXPERTS) ws[WS_CNT + c * N_EXPERTS + t] = run_base[t];
}

// ---------------------------------------------------------------------------
// emit_kernel: 64 blocks x 256. Cross-chip exclusive offsets (serialized chip
// order, as the reference), writes the inverse map + per-expert totals.
// ---------------------------------------------------------------------------
__global__ __launch_bounds__(256) void emit_kernel(const int* __restrict__ idx,
                                                   int* __restrict__ ws,
                                                   float* __restrict__ out) {
    __shared__ int cnt_s[NUM_CHIPS * N_EXPERTS];
    const int t = threadIdx.x;
    if (t < NUM_CHIPS * N_EXPERTS) cnt_s[t] = ws[WS_CNT + t];
    __syncthreads();

    const int a = blockIdx.x * 256 + t;       // global assignment id, 0..16383
    const int c = a >> 12;                    // uniform within a block
    const int n = a & (NPC - 1);
    const int e = idx[a];

    int off = 0;
    for (int cc = 0; cc < c; ++cc) off += cnt_s[cc * N_EXPERTS + e];
    const int dst = off + ws[WS_RANK + a];
    ws[WS_INV + e * MAX_TOK + dst] = (c << 12) | n;

    if (blockIdx.x == 0 && t < N_EXPERTS) {
        int s = cnt_s[t] + cnt_s[N_EXPERTS + t] + cnt_s[2 * N_EXPERTS + t] +
                cnt_s[3 * N_EXPERTS + t];
        ws[WS_TOT + t] = s;
        out[CNT_OFF + t] = (float)s;
    }
}

// ---------------------------------------------------------------------------
// scatter_kernel: 4 rows per 256-thread block (a 4-row group never straddles
// an expert boundary -> single tot load). All inv loads then all x-gather
// loads issued independently for MLP; buf/meta stores are nontemporal
// (write-once; keep L2 for the 32 MiB x, which is re-read ~4x).
// ---------------------------------------------------------------------------
__global__ __launch_bounds__(256) void scatter_kernel(const float* __restrict__ x,
                                                      const float* __restrict__ wts,
                                                      const int* __restrict__ ws,
                                                      float* __restrict__ out) {
    const int t = threadIdx.x;
    const int row0 = blockIdx.x * 4;
    const int e = row0 >> 10;
    const int slot0 = row0 & (MAX_TOK - 1);

    const int tot = ws[WS_TOT + e];

    int iv[4];
    bool occ[4];
#pragma unroll
    for (int r = 0; r < 4; ++r) {
        occ[r] = (slot0 + r) < tot;
        iv[r] = occ[r] ? ws[WS_INV + row0 + r] : 0;
    }

    vfloat4 v[4][2];
#pragma unroll
    for (int r = 0; r < 4; ++r) {
        if (occ[r]) {
            const int c = iv[r] >> 12;
            const int n = iv[r] & (NPC - 1);
            const vfloat4* src =
                (const vfloat4*)(x + ((size_t)c * SEQ + (n >> 2)) * HIDDEN);
            v[r][0] = src[t];
            v[r][1] = src[t + 256];
        } else {
            v[r][0] = (vfloat4)(0.f);
            v[r][1] = (vfloat4)(0.f);
        }
    }

#pragma unroll
    for (int r = 0; r < 4; ++r) {
        vfloat4* dst = (vfloat4*)(out + (size_t)(row0 + r) * HIDDEN);
        __builtin_nontemporal_store(v[r][0], dst + t);
        __builtin_nontemporal_store(v[r][1], dst + t + 256);

        if (t < META_LEN) {
            float mv = -1.0f;
            if (occ[r]) {
                const int c = iv[r] >> 12;
                const int n = iv[r] & (NPC - 1);
                mv = 0.0f;
                if (t == 0) mv = (float)c;
                else if (t == 1) mv = (float)(n >> 2);
                else if (t == 2) mv = (float)(n & 3);
                else if (t == 3) mv = (float)e;
                else if (t == 4) {
                    // bf16 bits of the routing weight, RNE (matches jax astype)
                    float wv = wts[c * NPC + n];
                    uint32_t ub;
                    memcpy(&ub, &wv, 4);
                    uint32_t lsb = (ub >> 16) & 1u;
                    uint32_t bits = (ub + 0x7FFFu + lsb) >> 16;
                    mv = (float)(int)(short)(uint16_t)bits;  // sign-extend int16
                }
            }
            __builtin_nontemporal_store(
                mv, out + META_OFF + (size_t)(row0 + r) * META_LEN + t);
        }
    }
}

extern "C" void kernel_launch(void* const* d_in, const int* in_sizes, int n_in,
                              void* d_out, int out_size, void* d_ws, size_t ws_size,
                              hipStream_t stream) {
    const float* x   = (const float*)d_in[0];   // [4,1024,2048] f32
    const float* wts = (const float*)d_in[1];   // [4,1024,4]    f32
    const int*   idx = (const int*)d_in[2];     // [4,1024,4]    i32
    float* out = (float*)d_out;
    int* ws = (int*)d_ws;

    rank_kernel<<<NUM_CHIPS, 1024, 0, stream>>>(idx, ws);
    emit_kernel<<<NTOT / 256, 256, 0, stream>>>(idx, ws, out);
    scatter_kernel<<<ROWS / 4, 256, 0, stream>>>(x, wts, ws, out);
}

// Round 5
// 300.313 us; speedup vs baseline: 1.0104x; 1.0104x over previous
//
#include <hip/hip_runtime.h>
#include <hip/hip_bf16.h>
#include <stdint.h>
#include <string.h>

// Problem constants (fixed by the reference)
#define NUM_CHIPS 4
#define N_EXPERTS 32
#define TOP_K 4
#define SEQ 1024
#define HIDDEN 2048
#define MAX_TOK 1024
#define META_LEN 8
#define NPC (SEQ * TOP_K)            // 4096 assignments per chip
#define NTOT (NUM_CHIPS * NPC)       // 16384 assignments total
#define ROWS (N_EXPERTS * MAX_TOK)   // 32768 output rows
#define BUF_ELEMS ((size_t)ROWS * HIDDEN)           // 67,108,864
#define META_OFF BUF_ELEMS
#define CNT_OFF (BUF_ELEMS + (size_t)ROWS * META_LEN)

// Workspace layout (ints)
#define WS_RANK 0                    // [NTOT]   within-chip stable rank
#define WS_CNT  (NTOT)               // [4][32]  per-chip per-expert counts

// Clang ext-vector type: __builtin_nontemporal_store accepts these
// (it rejects HIP's float4 class type).
typedef float vfloat4 __attribute__((ext_vector_type(4)));

// ---------------------------------------------------------------------------
// rank_kernel: one block per chip, 1024 threads. All 4096 expert ids loaded
// into registers up-front; 4 serial chunk iterations of ballot-rank +
// 16-wave LDS scan. Produces within-chip stable rank per assignment and the
// per-chip per-expert counts. ~4 us.
// ---------------------------------------------------------------------------
__global__ __launch_bounds__(1024) void rank_kernel(const int* __restrict__ idx,
                                                    int* __restrict__ ws) {
    __shared__ int run_base[N_EXPERTS];       // running per-expert count
    __shared__ int wave_cnt[16][N_EXPERTS];   // per-wave group sizes in chunk
    __shared__ int wave_base[16][N_EXPERTS];  // exclusive base per wave

    const int c = blockIdx.x;
    const int t = threadIdx.x;
    const int lane = t & 63;
    const int w = t >> 6;

    int e[4];
#pragma unroll
    for (int q = 0; q < 4; ++q) e[q] = idx[c * NPC + q * 1024 + t];

    if (t < N_EXPERTS) run_base[t] = 0;
    __syncthreads();

#pragma unroll
    for (int q = 0; q < 4; ++q) {
        if (t < 16 * N_EXPERTS) ((int*)wave_cnt)[t] = 0;
        __syncthreads();

        // mask of lanes in this wave routed to the same expert
        uint64_t m = ~0ull;
#pragma unroll
        for (int b = 0; b < 5; ++b) {
            uint64_t bb = __ballot((e[q] >> b) & 1);
            m &= ((e[q] >> b) & 1) ? bb : ~bb;
        }
        const int rk = __popcll(m & ((1ull << lane) - 1ull));  // stable in-wave rank
        if (rk == 0) wave_cnt[w][e[q]] = __popcll(m);          // group leader
        __syncthreads();

        // cross-wave exclusive scan per expert, update running base
        if (t < N_EXPERTS) {
            int s = run_base[t];
#pragma unroll
            for (int ww = 0; ww < 16; ++ww) {
                wave_base[ww][t] = s;
                s += wave_cnt[ww][t];
            }
            run_base[t] = s;
        }
        __syncthreads();

        ws[WS_RANK + c * NPC + q * 1024 + t] = wave_base[w][e[q]] + rk;
        // next writes to wave_base occur only after two more __syncthreads().
    }
    __syncthreads();
    if (t < N_EXPERTS) ws[WS_CNT + c * N_EXPERTS + t] = run_base[t];
}

// ---------------------------------------------------------------------------
// scatter_occ: token-driven. One block per (chip, token): reads the 8 KB x
// row ONCE, writes it to the K=4 destination slots (computed directly from
// the count table + precomputed rank — no inverse map). 4x less read
// traffic than slot-driven gather.
// ---------------------------------------------------------------------------
__global__ __launch_bounds__(256) void scatter_occ(const float* __restrict__ x,
                                                   const float* __restrict__ wts,
                                                   const int* __restrict__ idx,
                                                   const int* __restrict__ ws,
                                                   float* __restrict__ out) {
    __shared__ int cnt_s[NUM_CHIPS * N_EXPERTS];
    const int t = threadIdx.x;
    const int b = blockIdx.x;
    const int c = b >> 10;                 // chip
    const int tk = b & (SEQ - 1);          // token

    if (t < NUM_CHIPS * N_EXPERTS) cnt_s[t] = ws[WS_CNT + t];

    // this token's hidden vector (read once)
    const vfloat4* src = (const vfloat4*)(x + ((size_t)c * SEQ + tk) * HIDDEN);
    vfloat4 v0 = src[t];
    vfloat4 v1 = src[t + 256];

    int e[TOP_K], rk[TOP_K];
#pragma unroll
    for (int k = 0; k < TOP_K; ++k) {
        e[k] = idx[c * NPC + tk * TOP_K + k];
        rk[k] = ws[WS_RANK + c * NPC + tk * TOP_K + k];
    }
    __syncthreads();

#pragma unroll
    for (int k = 0; k < TOP_K; ++k) {
        // cross-chip exclusive offset (serialized chip order, as reference)
        int off = 0;
        for (int cc = 0; cc < c; ++cc) off += cnt_s[cc * N_EXPERTS + e[k]];
        const int row = e[k] * MAX_TOK + off + rk[k];

        vfloat4* dst = (vfloat4*)(out + (size_t)row * HIDDEN);
        __builtin_nontemporal_store(v0, dst + t);
        __builtin_nontemporal_store(v1, dst + t + 256);

        if (t < META_LEN) {
            float mv = 0.0f;
            if (t == 0) mv = (float)c;
            else if (t == 1) mv = (float)tk;
            else if (t == 2) mv = (float)k;
            else if (t == 3) mv = (float)e[k];
            else if (t == 4) {
                // bf16 bits of the routing weight, RNE (matches jax astype)
                float wv = wts[c * NPC + tk * TOP_K + k];
                uint32_t ub;
                memcpy(&ub, &wv, 4);
                uint32_t lsb = (ub >> 16) & 1u;
                uint32_t bits = (ub + 0x7FFFu + lsb) >> 16;
                mv = (float)(int)(short)(uint16_t)bits;  // sign-extend int16
            }
            __builtin_nontemporal_store(
                mv, out + META_OFF + (size_t)row * META_LEN + t);
        }
    }
}

// ---------------------------------------------------------------------------
// scatter_empty: 4 rows per block; zero-fills rows whose slot >= total[e]
// (near-pure-write streaming). Block 0 also emits the experts_counter output.
// ---------------------------------------------------------------------------
__global__ __launch_bounds__(256) void scatter_empty(const int* __restrict__ ws,
                                                     float* __restrict__ out) {
    const int t = threadIdx.x;
    const int row0 = blockIdx.x * 4;
    const int e = row0 >> 10;
    const int slot0 = row0 & (MAX_TOK - 1);

    const int tot = ws[WS_CNT + e] + ws[WS_CNT + N_EXPERTS + e] +
                    ws[WS_CNT + 2 * N_EXPERTS + e] + ws[WS_CNT + 3 * N_EXPERTS + e];

    if (blockIdx.x == 0 && t < N_EXPERTS) {
        int s = ws[WS_CNT + t] + ws[WS_CNT + N_EXPERTS + t] +
                ws[WS_CNT + 2 * N_EXPERTS + t] + ws[WS_CNT + 3 * N_EXPERTS + t];
        out[CNT_OFF + t] = (float)s;
    }

    if (slot0 + 3 < tot) return;              // fully occupied group: nothing to do

    const vfloat4 z = (vfloat4)(0.f);
#pragma unroll
    for (int r = 0; r < 4; ++r) {
        if (slot0 + r < tot) continue;        // occupied row handled by scatter_occ
        vfloat4* dst = (vfloat4*)(out + (size_t)(row0 + r) * HIDDEN);
        __builtin_nontemporal_store(z, dst + t);
        __builtin_nontemporal_store(z, dst + t + 256);
        if (t < META_LEN)
            __builtin_nontemporal_store(
                -1.0f, out + META_OFF + (size_t)(row0 + r) * META_LEN + t);
    }
}

extern "C" void kernel_launch(void* const* d_in, const int* in_sizes, int n_in,
                              void* d_out, int out_size, void* d_ws, size_t ws_size,
                              hipStream_t stream) {
    const float* x   = (const float*)d_in[0];   // [4,1024,2048] f32
    const float* wts = (const float*)d_in[1];   // [4,1024,4]    f32
    const int*   idx = (const int*)d_in[2];     // [4,1024,4]    i32
    float* out = (float*)d_out;
    int* ws = (int*)d_ws;

    rank_kernel<<<NUM_CHIPS, 1024, 0, stream>>>(idx, ws);
    scatter_empty<<<ROWS / 4, 256, 0, stream>>>(ws, out);
    scatter_occ<<<NUM_CHIPS * SEQ, 256, 0, stream>>>(x, wts, idx, ws, out);
}